// Round 4
// baseline (872.353 us; speedup 1.0000x reference)
//
#include <hip/hip_runtime.h>
#include <hip/hip_bf16.h>

typedef __hip_bfloat16 bf16;
typedef short s16x8 __attribute__((ext_vector_type(8)));
typedef unsigned short u16x8 __attribute__((ext_vector_type(8)));
typedef float f32x4 __attribute__((ext_vector_type(4)));

#define T_TOK 2048
#define HDIM  2048
#define NEXP  64
#define IDIM  768
#define TOPK  8
#define OUT_OFF (T_TOK * HDIM)
#define NPAIR (T_TOK * TOPK)

#define WS_TOPK_IDX  0
#define WS_TOPK_W    (64 * 1024)
#define WS_PAIR_TOK  (128 * 1024)
#define WS_SLOT_OF   (192 * 1024)
#define WS_COUNTS    (256 * 1024)
#define WS_OFFSETS   (257 * 1024)
#define WS_CURSOR    (258 * 1024)
#define WS_H         (1024 * 1024)             // bf16 [NPAIR][IDIM]
#define WS_PARTIAL   (WS_H + (size_t)NPAIR * IDIM * 2)  // bf16 [NPAIR][HDIM]
#define WS_XB        WS_PARTIAL                // bf16 [T][H] (dead before partial written)

__device__ __forceinline__ float bf_to_f(unsigned short u) {
    return __uint_as_float(((unsigned int)u) << 16);
}
__device__ __forceinline__ unsigned short f2bf(float f) {
    unsigned int u = __float_as_uint(f);
    unsigned int r = (u + 0x7FFFu + ((u >> 16) & 1u)) >> 16;
    return (unsigned short)r;
}
__device__ __forceinline__ unsigned cvtpk(float lo, float hi) {
    unsigned r;
    asm("v_cvt_pk_bf16_f32 %0, %1, %2" : "=v"(r) : "v"(lo), "v"(hi));
    return r;
}

typedef const __attribute__((address_space(1))) unsigned int* gas_ptr;
typedef __attribute__((address_space(3))) unsigned int* las_ptr;
__device__ __forceinline__ void gload_lds16(const void* g, void* l) {
    __builtin_amdgcn_global_load_lds((gas_ptr)g, (las_ptr)l, 16, 0, 0);
}

// ---------------- kernel 0: x fp32 -> bf16 ----------------
__global__ __launch_bounds__(256) void xbf_kernel(const float* __restrict__ x,
                                                  unsigned short* __restrict__ xb) {
    int i = blockIdx.x * 256 + threadIdx.x;
    const float4* src = (const float4*)x + (size_t)i * 2;
    float4 a = src[0], b = src[1];
    u16x8 o;
    o[0] = f2bf(a.x); o[1] = f2bf(a.y); o[2] = f2bf(a.z); o[3] = f2bf(a.w);
    o[4] = f2bf(b.x); o[5] = f2bf(b.y); o[6] = f2bf(b.z); o[7] = f2bf(b.w);
    ((u16x8*)xb)[i] = o;
}

// ---------------- kernel 1: router logits ----------------
__global__ __launch_bounds__(256) void router_kernel(
    const float* __restrict__ x, const float* __restrict__ rw,
    float* __restrict__ logits) {
    int wave = threadIdx.x >> 6;
    int lane = threadIdx.x & 63;
    int t = blockIdx.x * 4 + wave;
    const float4* x4 = (const float4*)(x + (size_t)t * HDIM);
    float acc = 0.f;
    for (int h4 = 0; h4 < HDIM / 4; ++h4) {
        float4 xv = x4[h4];
        int h = h4 * 4;
        acc = fmaf(xv.x, rw[(h + 0) * NEXP + lane], acc);
        acc = fmaf(xv.y, rw[(h + 1) * NEXP + lane], acc);
        acc = fmaf(xv.z, rw[(h + 2) * NEXP + lane], acc);
        acc = fmaf(xv.w, rw[(h + 3) * NEXP + lane], acc);
    }
    logits[t * NEXP + lane] = acc;
}

// ---------------- kernel 2: softmax + top-8 ----------------
__global__ __launch_bounds__(64) void topk_kernel(
    const float* __restrict__ logits, int* __restrict__ topk_idx,
    float* __restrict__ topk_w, int* __restrict__ counts) {
    int t = blockIdx.x;
    int lane = threadIdx.x;
    float lg = logits[t * NEXP + lane];
    float mx = lg;
    for (int off = 32; off; off >>= 1) mx = fmaxf(mx, __shfl_xor(mx, off));
    float ex = expf(lg - mx);
    float sum = ex;
    for (int off = 32; off; off >>= 1) sum += __shfl_xor(sum, off);
    float prob = ex / sum;

    float pr = prob;
    float myv = 0.f;
    int myidx = 0;
    float ksum = 0.f;
    for (int k = 0; k < TOPK; ++k) {
        float v = pr;
        int idx = lane;
        for (int off = 32; off; off >>= 1) {
            float ov = __shfl_xor(v, off);
            int oi = __shfl_xor(idx, off);
            if (ov > v || (ov == v && oi < idx)) { v = ov; idx = oi; }
        }
        ksum += v;
        if (lane == k) { myidx = idx; myv = v; }
        if (lane == idx) pr = -1.f;
    }
    if (lane < TOPK) {
        topk_idx[t * TOPK + lane] = myidx;
        topk_w[t * TOPK + lane] = myv / ksum;
        atomicAdd(&counts[myidx], 1);
    }
}

// ---------------- kernel 3: scan ----------------
__global__ __launch_bounds__(64) void scan_kernel(
    const int* __restrict__ counts, int* __restrict__ offsets, int* __restrict__ cursor) {
    int lane = threadIdx.x;
    int c = counts[lane];
    int incl = c;
    for (int off = 1; off < 64; off <<= 1) {
        int tt = __shfl_up(incl, off);
        if (lane >= off) incl += tt;
    }
    offsets[lane] = incl - c;
    if (lane == 63) offsets[64] = incl;
    cursor[lane] = 0;
}

// ---------------- kernel 4: scatter ----------------
__global__ __launch_bounds__(256) void scatter_kernel(
    const int* __restrict__ topk_idx, const int* __restrict__ offsets,
    int* __restrict__ cursor, int* __restrict__ pair_token, int* __restrict__ slot_of) {
    int i = blockIdx.x * 256 + threadIdx.x;
    if (i >= NPAIR) return;
    int t = i >> 3;
    int e = topk_idx[i];
    int pos = atomicAdd(&cursor[e], 1);
    int slot = offsets[e] + pos;
    pair_token[slot] = t;
    slot_of[i] = slot;
}

// ================= MFMA grouped GEMMs =================
#define BM   128
#define BKS  64

// ---------------- kernel 5: gateup ----------------
// grid (e, mt2-stride, ntile 12); 4 waves (2x2); wave: 64m x 32n, g+u.
// A: global_load_lds (chunk-XOR swizzled src) dbuf, linear [m][64].
// B: float2 reg-stage -> cvt_pk -> b128 write into [n][64] with chunk-XOR
//    slot (c ^ ((n>>1)&7)); reads use the same XOR -> bank-floor both sides.
__global__ __launch_bounds__(256) void gateup_mfma(
    const unsigned short* __restrict__ xb, const float* __restrict__ gate_w,
    const float* __restrict__ up_w, const int* __restrict__ offsets,
    const int* __restrict__ pair_token, unsigned short* __restrict__ hbuf) {
    int e = blockIdx.x;
    int ntile = blockIdx.z;
    int off = offsets[e];
    int cnt = offsets[e + 1] - off;
    if (cnt <= 0) return;

    __shared__ unsigned short As[2][BM * BKS];     // 32 KB
    __shared__ unsigned short Bg[2][64 * BKS];     // 16 KB
    __shared__ unsigned short Bu[2][64 * BKS];     // 16 KB
    __shared__ int toks[BM];

    int tid = threadIdx.x;
    int lane = tid & 63;
    int wave = tid >> 6;
    int wr = wave >> 1, wc = wave & 1;
    int l15 = lane & 15, lg4 = lane >> 4;

    // B staging map: thread = (n-pair nI2, chunk kC)
    int nI2 = tid & 31;          // n-pair 0..31 -> n = 2*nI2, 2*nI2+1
    int kC  = tid >> 5;          // k-chunk 0..7 (8 k each)
    int bn0 = nI2 * 2;
    int wslot = (kC ^ (nI2 & 7)) * 8;   // swizzled slot (u16 units)
    const float* gp = gate_w + (size_t)e * HDIM * IDIM + (size_t)(kC * 8) * IDIM + ntile * 64 + bn0;
    const float* upp = up_w  + (size_t)e * HDIM * IDIM + (size_t)(kC * 8) * IDIM + ntile * 64 + bn0;

    for (int mt = blockIdx.y; mt * BM < cnt; mt += gridDim.y) {
        int m0 = mt * BM;
        if (tid < BM) {
            int p = m0 + tid;
            toks[tid] = pair_token[off + (p < cnt ? p : 0)];
        }
        __syncthreads();
        const unsigned short* aq[4];
        #pragma unroll
        for (int q = 0; q < 4; ++q) {
            int mloc = q * 32 + wave * 8 + (lane >> 3);
            int j2 = (lane & 7) ^ (mloc & 7);
            aq[q] = xb + (size_t)toks[mloc] * HDIM + j2 * 8;
        }
        f32x4 accg[4][2] = {};
        f32x4 accu[4][2] = {};

        // prologue: issue A[0], load B[0] regs (float2, coalesced)
        #pragma unroll
        for (int q = 0; q < 4; ++q)
            gload_lds16(aq[q], &As[0][(q * 256 + wave * 64) * 8]);
        float2 G2[8], U2[8];
        #pragma unroll
        for (int i = 0; i < 8; ++i) {
            G2[i] = *(const float2*)(gp + (size_t)i * IDIM);
            U2[i] = *(const float2*)(upp + (size_t)i * IDIM);
        }

        for (int ks = 0; ks < HDIM / BKS; ++ks) {
            int p = ks & 1;
            // 1. cvt + b128 write B[ks] into buf p (one 16B chunk per row)
            {
                uint4 wg0, wg1, wu0, wu1;
                wg0.x = cvtpk(G2[0].x, G2[1].x); wg0.y = cvtpk(G2[2].x, G2[3].x);
                wg0.z = cvtpk(G2[4].x, G2[5].x); wg0.w = cvtpk(G2[6].x, G2[7].x);
                wg1.x = cvtpk(G2[0].y, G2[1].y); wg1.y = cvtpk(G2[2].y, G2[3].y);
                wg1.z = cvtpk(G2[4].y, G2[5].y); wg1.w = cvtpk(G2[6].y, G2[7].y);
                wu0.x = cvtpk(U2[0].x, U2[1].x); wu0.y = cvtpk(U2[2].x, U2[3].x);
                wu0.z = cvtpk(U2[4].x, U2[5].x); wu0.w = cvtpk(U2[6].x, U2[7].x);
                wu1.x = cvtpk(U2[0].y, U2[1].y); wu1.y = cvtpk(U2[2].y, U2[3].y);
                wu1.z = cvtpk(U2[4].y, U2[5].y); wu1.w = cvtpk(U2[6].y, U2[7].y);
                *(uint4*)&Bg[p][bn0 * BKS + wslot] = wg0;
                *(uint4*)&Bg[p][(bn0 + 1) * BKS + wslot] = wg1;
                *(uint4*)&Bu[p][bn0 * BKS + wslot] = wu0;
                *(uint4*)&Bu[p][(bn0 + 1) * BKS + wslot] = wu1;
            }
            // 2. barrier (drains A gloads for buf p and LDS writes)
            __syncthreads();
            // 3. issue next-step loads (fly under MFMA)
            if (ks + 1 < HDIM / BKS) {
                int h1 = (ks + 1) * BKS;
                #pragma unroll
                for (int q = 0; q < 4; ++q)
                    gload_lds16(aq[q] + h1, &As[p ^ 1][(q * 256 + wave * 64) * 8]);
                #pragma unroll
                for (int i = 0; i < 8; ++i) {
                    G2[i] = *(const float2*)(gp + (size_t)(h1 + i) * IDIM);
                    U2[i] = *(const float2*)(upp + (size_t)(h1 + i) * IDIM);
                }
            }
            // 4. MFMA on buf p
            #pragma unroll
            for (int kk = 0; kk < 2; ++kk) {
                int jk = kk * 4 + lg4;
                s16x8 a[4], bg2[2], bu2[2];
                #pragma unroll
                for (int mr = 0; mr < 4; ++mr) {
                    int r = wr * 64 + mr * 16 + l15;
                    a[mr] = *(const s16x8*)&As[p][r * BKS + ((jk ^ (r & 7)) * 8)];
                }
                #pragma unroll
                for (int nr = 0; nr < 2; ++nr) {
                    int row = wc * 32 + nr * 16 + l15;
                    int slot = (jk ^ ((row >> 1) & 7)) * 8;
                    bg2[nr] = *(const s16x8*)&Bg[p][row * BKS + slot];
                    bu2[nr] = *(const s16x8*)&Bu[p][row * BKS + slot];
                }
                #pragma unroll
                for (int mr = 0; mr < 4; ++mr)
                    #pragma unroll
                    for (int nr = 0; nr < 2; ++nr) {
                        accg[mr][nr] = __builtin_amdgcn_mfma_f32_16x16x32_bf16(
                            a[mr], bg2[nr], accg[mr][nr], 0, 0, 0);
                        accu[mr][nr] = __builtin_amdgcn_mfma_f32_16x16x32_bf16(
                            a[mr], bu2[nr], accu[mr][nr], 0, 0, 0);
                    }
            }
        }

        // epilogue: h = silu(g)*u
        #pragma unroll
        for (int mr = 0; mr < 4; ++mr)
            #pragma unroll
            for (int nr = 0; nr < 2; ++nr) {
                int col = ntile * 64 + wc * 32 + nr * 16 + l15;
                #pragma unroll
                for (int reg = 0; reg < 4; ++reg) {
                    int r = m0 + wr * 64 + mr * 16 + lg4 * 4 + reg;
                    if (r < cnt) {
                        float g = accg[mr][nr][reg];
                        float u = accu[mr][nr][reg];
                        float hv = (g / (1.f + __expf(-g))) * u;
                        hbuf[(size_t)(off + r) * IDIM + col] = f2bf(hv);
                    }
                }
            }
        __syncthreads();
    }
}

// ---------------- kernel 6: down ----------------
// grid (e, mt2-stride, ntile 16); BN=128; waves 2x2, each 64x64.
__global__ __launch_bounds__(256) void down_mfma(
    const unsigned short* __restrict__ hbuf, const float* __restrict__ down_w,
    const int* __restrict__ offsets, unsigned short* __restrict__ partial) {
    int e = blockIdx.x;
    int ntile = blockIdx.z;
    int off = offsets[e];
    int cnt = offsets[e + 1] - off;
    if (cnt <= 0) return;

    __shared__ unsigned short As[2][BM * BKS];     // 32 KB
    __shared__ unsigned short Bd[2][128 * BKS];    // 32 KB

    int tid = threadIdx.x;
    int lane = tid & 63;
    int wave = tid >> 6;
    int wr = wave >> 1, wc = wave & 1;
    int l15 = lane & 15, lg4 = lane >> 4;

    // B staging map: thread = (n-pair nI2 0..63, chunk kC0 = wave 0..3, +4)
    int nI2 = tid & 63;
    int kC0 = tid >> 6;
    int bn0 = nI2 * 2;
    int wslotA = (kC0 ^ (nI2 & 7)) * 8;
    int wslotB = ((kC0 + 4) ^ (nI2 & 7)) * 8;
    const float* dp = down_w + (size_t)e * IDIM * HDIM + ntile * 128 + bn0;

    for (int mt = blockIdx.y; mt * BM < cnt; mt += gridDim.y) {
        int m0 = mt * BM;
        const unsigned short* aq[4];
        #pragma unroll
        for (int q = 0; q < 4; ++q) {
            int mloc = q * 32 + wave * 8 + (lane >> 3);
            int row = m0 + mloc;
            if (row >= cnt) row = cnt - 1;
            int j2 = (lane & 7) ^ (mloc & 7);
            aq[q] = hbuf + (size_t)(off + row) * IDIM + j2 * 8;
        }
        f32x4 acc[4][4] = {};

        // prologue
        #pragma unroll
        for (int q = 0; q < 4; ++q)
            gload_lds16(aq[q], &As[0][(q * 256 + wave * 64) * 8]);
        float2 Da[8], Db[8];
        #pragma unroll
        for (int i = 0; i < 8; ++i) {
            Da[i] = *(const float2*)(dp + (size_t)(kC0 * 8 + i) * HDIM);
            Db[i] = *(const float2*)(dp + (size_t)(kC0 * 8 + 32 + i) * HDIM);
        }

        for (int ks = 0; ks < IDIM / BKS; ++ks) {
            int p = ks & 1;
            {
                uint4 w0, w1, w2, w3;
                w0.x = cvtpk(Da[0].x, Da[1].x); w0.y = cvtpk(Da[2].x, Da[3].x);
                w0.z = cvtpk(Da[4].x, Da[5].x); w0.w = cvtpk(Da[6].x, Da[7].x);
                w1.x = cvtpk(Da[0].y, Da[1].y); w1.y = cvtpk(Da[2].y, Da[3].y);
                w1.z = cvtpk(Da[4].y, Da[5].y); w1.w = cvtpk(Da[6].y, Da[7].y);
                w2.x = cvtpk(Db[0].x, Db[1].x); w2.y = cvtpk(Db[2].x, Db[3].x);
                w2.z = cvtpk(Db[4].x, Db[5].x); w2.w = cvtpk(Db[6].x, Db[7].x);
                w3.x = cvtpk(Db[0].y, Db[1].y); w3.y = cvtpk(Db[2].y, Db[3].y);
                w3.z = cvtpk(Db[4].y, Db[5].y); w3.w = cvtpk(Db[6].y, Db[7].y);
                *(uint4*)&Bd[p][bn0 * BKS + wslotA] = w0;
                *(uint4*)&Bd[p][(bn0 + 1) * BKS + wslotA] = w1;
                *(uint4*)&Bd[p][bn0 * BKS + wslotB] = w2;
                *(uint4*)&Bd[p][(bn0 + 1) * BKS + wslotB] = w3;
            }
            __syncthreads();
            if (ks + 1 < IDIM / BKS) {
                int k1 = (ks + 1) * BKS;
                #pragma unroll
                for (int q = 0; q < 4; ++q)
                    gload_lds16(aq[q] + k1, &As[p ^ 1][(q * 256 + wave * 64) * 8]);
                #pragma unroll
                for (int i = 0; i < 8; ++i) {
                    Da[i] = *(const float2*)(dp + (size_t)(k1 + kC0 * 8 + i) * HDIM);
                    Db[i] = *(const float2*)(dp + (size_t)(k1 + kC0 * 8 + 32 + i) * HDIM);
                }
            }
            #pragma unroll
            for (int kk = 0; kk < 2; ++kk) {
                int jk = kk * 4 + lg4;
                s16x8 a[4], b[4];
                #pragma unroll
                for (int mr = 0; mr < 4; ++mr) {
                    int r = wr * 64 + mr * 16 + l15;
                    a[mr] = *(const s16x8*)&As[p][r * BKS + ((jk ^ (r & 7)) * 8)];
                }
                #pragma unroll
                for (int nr = 0; nr < 4; ++nr) {
                    int row = wc * 64 + nr * 16 + l15;
                    int slot = (jk ^ ((row >> 1) & 7)) * 8;
                    b[nr] = *(const s16x8*)&Bd[p][row * BKS + slot];
                }
                #pragma unroll
                for (int mr = 0; mr < 4; ++mr)
                    #pragma unroll
                    for (int nr = 0; nr < 4; ++nr)
                        acc[mr][nr] = __builtin_amdgcn_mfma_f32_16x16x32_bf16(
                            a[mr], b[nr], acc[mr][nr], 0, 0, 0);
            }
        }

        #pragma unroll
        for (int mr = 0; mr < 4; ++mr)
            #pragma unroll
            for (int nr = 0; nr < 4; ++nr) {
                int col = ntile * 128 + wc * 64 + nr * 16 + l15;
                #pragma unroll
                for (int reg = 0; reg < 4; ++reg) {
                    int r = m0 + wr * 64 + mr * 16 + lg4 * 4 + reg;
                    if (r < cnt)
                        partial[(size_t)(off + r) * HDIM + col] = f2bf(acc[mr][nr][reg]);
                }
            }
        __syncthreads();
    }
}

// ---------------- kernel 7: weighted reduce ----------------
__global__ __launch_bounds__(256) void reduce_kernel(
    const unsigned short* __restrict__ partial, const int* __restrict__ slot_of,
    const float* __restrict__ topk_w, float* __restrict__ out) {
    int t = blockIdx.x;
    int j8 = threadIdx.x * 8;
    __shared__ int ss[8];
    __shared__ float sw[8];
    if (threadIdx.x < 8) {
        ss[threadIdx.x] = slot_of[t * TOPK + threadIdx.x];
        sw[threadIdx.x] = topk_w[t * TOPK + threadIdx.x];
    }
    __syncthreads();
    float acc[8] = {};
    #pragma unroll
    for (int k = 0; k < TOPK; ++k) {
        u16x8 v = *(const u16x8*)&partial[(size_t)ss[k] * HDIM + j8];
        float w = sw[k];
        #pragma unroll
        for (int i = 0; i < 8; ++i)
            acc[i] = fmaf(w, bf_to_f((unsigned short)v[i]), acc[i]);
    }
    float4 o0 = {acc[0], acc[1], acc[2], acc[3]};
    float4 o1 = {acc[4], acc[5], acc[6], acc[7]};
    *(float4*)&out[(size_t)t * HDIM + j8] = o0;
    *(float4*)&out[(size_t)t * HDIM + j8 + 4] = o1;
}

extern "C" void kernel_launch(void* const* d_in, const int* in_sizes, int n_in,
                              void* d_out, int out_size, void* d_ws, size_t ws_size,
                              hipStream_t stream) {
    const float* x  = (const float*)d_in[0];
    const float* rw = (const float*)d_in[1];
    const float* gw = (const float*)d_in[2];
    const float* uw = (const float*)d_in[3];
    const float* dw = (const float*)d_in[4];
    float* out = (float*)d_out;
    float* logits = out + OUT_OFF;

    char* ws = (char*)d_ws;
    int*   topk_idx   = (int*)(ws + WS_TOPK_IDX);
    float* topk_w     = (float*)(ws + WS_TOPK_W);
    int*   pair_token = (int*)(ws + WS_PAIR_TOK);
    int*   slot_of    = (int*)(ws + WS_SLOT_OF);
    int*   counts     = (int*)(ws + WS_COUNTS);
    int*   offsets    = (int*)(ws + WS_OFFSETS);
    int*   cursor     = (int*)(ws + WS_CURSOR);
    unsigned short* hbuf    = (unsigned short*)(ws + WS_H);
    unsigned short* partial = (unsigned short*)(ws + WS_PARTIAL);
    unsigned short* xb      = (unsigned short*)(ws + WS_XB);

    hipMemsetAsync(counts, 0, NEXP * sizeof(int), stream);
    xbf_kernel<<<T_TOK * HDIM / (256 * 8), 256, 0, stream>>>(x, xb);
    router_kernel<<<T_TOK / 4, 256, 0, stream>>>(x, rw, logits);
    topk_kernel<<<T_TOK, 64, 0, stream>>>(logits, topk_idx, topk_w, counts);
    scan_kernel<<<1, 64, 0, stream>>>(counts, offsets, cursor);
    scatter_kernel<<<NPAIR / 256, 256, 0, stream>>>(topk_idx, offsets, cursor, pair_token, slot_of);
    gateup_mfma<<<dim3(NEXP, 2, IDIM / 64), 256, 0, stream>>>(xb, gw, uw, offsets, pair_token, hbuf);
    down_mfma<<<dim3(NEXP, 2, HDIM / 128), 256, 0, stream>>>(hbuf, dw, offsets, partial);
    reduce_kernel<<<dim3(T_TOK, 1), 256, 0, stream>>>(partial, slot_of, topk_w, out);
}

// Round 5
// 674.113 us; speedup vs baseline: 1.2941x; 1.2941x over previous
//
#include <hip/hip_runtime.h>
#include <hip/hip_bf16.h>

typedef __hip_bfloat16 bf16;
typedef short s16x8 __attribute__((ext_vector_type(8)));
typedef unsigned short u16x8 __attribute__((ext_vector_type(8)));
typedef float f32x4 __attribute__((ext_vector_type(4)));

#define T_TOK 2048
#define HDIM  2048
#define NEXP  64
#define IDIM  768
#define TOPK  8
#define OUT_OFF (T_TOK * HDIM)
#define NPAIR (T_TOK * TOPK)

#define WS_TOPK_IDX  0
#define WS_TOPK_W    (64 * 1024)
#define WS_PAIR_TOK  (128 * 1024)
#define WS_SLOT_OF   (192 * 1024)
#define WS_COUNTS    (256 * 1024)
#define WS_OFFSETS   (257 * 1024)
#define WS_CURSOR    (258 * 1024)
#define WS_H         (1024 * 1024)             // bf16 [NPAIR][IDIM]
#define WS_PARTIAL   (WS_H + (size_t)NPAIR * IDIM * 2)  // bf16 [NPAIR][HDIM]
#define WS_XB        WS_PARTIAL                // bf16 [T][H] (dead before partial written)

__device__ __forceinline__ float bf_to_f(unsigned short u) {
    return __uint_as_float(((unsigned int)u) << 16);
}
__device__ __forceinline__ unsigned short f2bf(float f) {
    unsigned int u = __float_as_uint(f);
    unsigned int r = (u + 0x7FFFu + ((u >> 16) & 1u)) >> 16;
    return (unsigned short)r;
}
__device__ __forceinline__ unsigned cvtpk(float lo, float hi) {
    unsigned r;
    asm("v_cvt_pk_bf16_f32 %0, %1, %2" : "=v"(r) : "v"(lo), "v"(hi));
    return r;
}

typedef const __attribute__((address_space(1))) unsigned int* gas_ptr;
typedef __attribute__((address_space(3))) unsigned int* las_ptr;
__device__ __forceinline__ void gload_lds16(const void* g, void* l) {
    __builtin_amdgcn_global_load_lds((gas_ptr)g, (las_ptr)l, 16, 0, 0);
}

// ---------------- kernel 0: x fp32 -> bf16 ----------------
__global__ __launch_bounds__(256) void xbf_kernel(const float* __restrict__ x,
                                                  unsigned short* __restrict__ xb) {
    int i = blockIdx.x * 256 + threadIdx.x;
    const float4* src = (const float4*)x + (size_t)i * 2;
    float4 a = src[0], b = src[1];
    u16x8 o;
    o[0] = f2bf(a.x); o[1] = f2bf(a.y); o[2] = f2bf(a.z); o[3] = f2bf(a.w);
    o[4] = f2bf(b.x); o[5] = f2bf(b.y); o[6] = f2bf(b.z); o[7] = f2bf(b.w);
    ((u16x8*)xb)[i] = o;
}

// ---------------- kernel 1: router logits ----------------
__global__ __launch_bounds__(256) void router_kernel(
    const float* __restrict__ x, const float* __restrict__ rw,
    float* __restrict__ logits) {
    int wave = threadIdx.x >> 6;
    int lane = threadIdx.x & 63;
    int t = blockIdx.x * 4 + wave;
    const float4* x4 = (const float4*)(x + (size_t)t * HDIM);
    float acc = 0.f;
    for (int h4 = 0; h4 < HDIM / 4; ++h4) {
        float4 xv = x4[h4];
        int h = h4 * 4;
        acc = fmaf(xv.x, rw[(h + 0) * NEXP + lane], acc);
        acc = fmaf(xv.y, rw[(h + 1) * NEXP + lane], acc);
        acc = fmaf(xv.z, rw[(h + 2) * NEXP + lane], acc);
        acc = fmaf(xv.w, rw[(h + 3) * NEXP + lane], acc);
    }
    logits[t * NEXP + lane] = acc;
}

// ---------------- kernel 2: softmax + top-8 ----------------
__global__ __launch_bounds__(64) void topk_kernel(
    const float* __restrict__ logits, int* __restrict__ topk_idx,
    float* __restrict__ topk_w, int* __restrict__ counts) {
    int t = blockIdx.x;
    int lane = threadIdx.x;
    float lg = logits[t * NEXP + lane];
    float mx = lg;
    for (int off = 32; off; off >>= 1) mx = fmaxf(mx, __shfl_xor(mx, off));
    float ex = expf(lg - mx);
    float sum = ex;
    for (int off = 32; off; off >>= 1) sum += __shfl_xor(sum, off);
    float prob = ex / sum;

    float pr = prob;
    float myv = 0.f;
    int myidx = 0;
    float ksum = 0.f;
    for (int k = 0; k < TOPK; ++k) {
        float v = pr;
        int idx = lane;
        for (int off = 32; off; off >>= 1) {
            float ov = __shfl_xor(v, off);
            int oi = __shfl_xor(idx, off);
            if (ov > v || (ov == v && oi < idx)) { v = ov; idx = oi; }
        }
        ksum += v;
        if (lane == k) { myidx = idx; myv = v; }
        if (lane == idx) pr = -1.f;
    }
    if (lane < TOPK) {
        topk_idx[t * TOPK + lane] = myidx;
        topk_w[t * TOPK + lane] = myv / ksum;
        atomicAdd(&counts[myidx], 1);
    }
}

// ---------------- kernel 3: scan ----------------
__global__ __launch_bounds__(64) void scan_kernel(
    const int* __restrict__ counts, int* __restrict__ offsets, int* __restrict__ cursor) {
    int lane = threadIdx.x;
    int c = counts[lane];
    int incl = c;
    for (int off = 1; off < 64; off <<= 1) {
        int tt = __shfl_up(incl, off);
        if (lane >= off) incl += tt;
    }
    offsets[lane] = incl - c;
    if (lane == 63) offsets[64] = incl;
    cursor[lane] = 0;
}

// ---------------- kernel 4: scatter ----------------
__global__ __launch_bounds__(256) void scatter_kernel(
    const int* __restrict__ topk_idx, const int* __restrict__ offsets,
    int* __restrict__ cursor, int* __restrict__ pair_token, int* __restrict__ slot_of) {
    int i = blockIdx.x * 256 + threadIdx.x;
    if (i >= NPAIR) return;
    int t = i >> 3;
    int e = topk_idx[i];
    int pos = atomicAdd(&cursor[e], 1);
    int slot = offsets[e] + pos;
    pair_token[slot] = t;
    slot_of[i] = slot;
}

// ================= MFMA grouped GEMMs (512 thr, 8 waves) =================
#define BM   128
#define BKS  64

// ---------------- kernel 5: gateup ----------------
// grid (e, mt4-stride, ntile 12); 8 waves = 2wr x 4wc; wave: 64m x 16i (g AND u).
__global__ __launch_bounds__(512, 4) void gateup_mfma(
    const unsigned short* __restrict__ xb, const float* __restrict__ gate_w,
    const float* __restrict__ up_w, const int* __restrict__ offsets,
    const int* __restrict__ pair_token, unsigned short* __restrict__ hbuf) {
    int e = blockIdx.x;
    int ntile = blockIdx.z;
    int off = offsets[e];
    int cnt = offsets[e + 1] - off;
    if (cnt <= 0) return;

    __shared__ unsigned short As[2][BM * BKS];      // 16 KB x2, linear [m][64k] swz
    __shared__ unsigned short Bgu[2][BM * BKS];     // rows 0-63 g, 64-127 u, [n][64k] swz
    __shared__ int toks[BM];

    int tid = threadIdx.x;
    int lane = tid & 63;
    int wave = tid >> 6;
    int wr = wave >> 2, wc = wave & 3;
    int l15 = lane & 15, lg4 = lane >> 4;

    // B staging map: 512 thr = 2 mat x 32 n-pair x 8 k-chunk
    int mat = tid >> 8;
    int t8 = tid & 255;
    int nI2 = t8 & 31, kC = t8 >> 5;
    int brow0 = mat * 64 + nI2 * 2;
    int bslot = (kC ^ (nI2 & 7)) * 8;
    const float* bsrc = (mat ? up_w : gate_w) + (size_t)e * HDIM * IDIM
                        + (size_t)(kC * 8) * IDIM + ntile * 64 + nI2 * 2;

    // A staging: per q in {0,1}: row = q*64 + tid>>3, chunk = (tid&7) ^ (row&7)
    for (int mt = blockIdx.y; mt * BM < cnt; mt += gridDim.y) {
        int m0 = mt * BM;
        if (tid < BM) {
            int p = m0 + tid;
            toks[tid] = pair_token[off + (p < cnt ? p : 0)];
        }
        __syncthreads();
        const unsigned short* aq[2];
        #pragma unroll
        for (int q = 0; q < 2; ++q) {
            int row = q * 64 + (tid >> 3);
            aq[q] = xb + (size_t)toks[row] * HDIM + (((tid & 7) ^ (row & 7)) * 8);
        }
        f32x4 accg[4] = {};
        f32x4 accu[4] = {};

        // prologue
        #pragma unroll
        for (int q = 0; q < 2; ++q)
            gload_lds16(aq[q], &As[0][(q * 512 + tid) * 8]);
        float2 Bv[8];
        #pragma unroll
        for (int i = 0; i < 8; ++i)
            Bv[i] = *(const float2*)(bsrc + (size_t)i * IDIM);

        for (int ks = 0; ks < HDIM / BKS; ++ks) {
            int p = ks & 1;
            {
                uint4 w0, w1;
                w0.x = cvtpk(Bv[0].x, Bv[1].x); w0.y = cvtpk(Bv[2].x, Bv[3].x);
                w0.z = cvtpk(Bv[4].x, Bv[5].x); w0.w = cvtpk(Bv[6].x, Bv[7].x);
                w1.x = cvtpk(Bv[0].y, Bv[1].y); w1.y = cvtpk(Bv[2].y, Bv[3].y);
                w1.z = cvtpk(Bv[4].y, Bv[5].y); w1.w = cvtpk(Bv[6].y, Bv[7].y);
                *(uint4*)&Bgu[p][brow0 * BKS + bslot] = w0;
                *(uint4*)&Bgu[p][(brow0 + 1) * BKS + bslot] = w1;
            }
            __syncthreads();
            if (ks + 1 < HDIM / BKS) {
                int h1 = (ks + 1) * BKS;
                #pragma unroll
                for (int q = 0; q < 2; ++q)
                    gload_lds16(aq[q] + h1, &As[p ^ 1][(q * 512 + tid) * 8]);
                #pragma unroll
                for (int i = 0; i < 8; ++i)
                    Bv[i] = *(const float2*)(bsrc + (size_t)(h1 + i) * IDIM);
            }
            #pragma unroll
            for (int kk = 0; kk < 2; ++kk) {
                int jk = kk * 4 + lg4;
                s16x8 a[4], bg, bu;
                #pragma unroll
                for (int mr = 0; mr < 4; ++mr) {
                    int r = wr * 64 + mr * 16 + l15;
                    a[mr] = *(const s16x8*)&As[p][r * BKS + ((jk ^ (r & 7)) * 8)];
                }
                int rg = wc * 16 + l15;
                int ru = 64 + rg;
                bg = *(const s16x8*)&Bgu[p][rg * BKS + ((jk ^ ((rg >> 1) & 7)) * 8)];
                bu = *(const s16x8*)&Bgu[p][ru * BKS + ((jk ^ ((ru >> 1) & 7)) * 8)];
                #pragma unroll
                for (int mr = 0; mr < 4; ++mr) {
                    accg[mr] = __builtin_amdgcn_mfma_f32_16x16x32_bf16(a[mr], bg, accg[mr], 0, 0, 0);
                    accu[mr] = __builtin_amdgcn_mfma_f32_16x16x32_bf16(a[mr], bu, accu[mr], 0, 0, 0);
                }
            }
        }

        // epilogue: h = silu(g)*u
        int col = ntile * 64 + wc * 16 + l15;
        #pragma unroll
        for (int mr = 0; mr < 4; ++mr) {
            #pragma unroll
            for (int reg = 0; reg < 4; ++reg) {
                int r = m0 + wr * 64 + mr * 16 + lg4 * 4 + reg;
                if (r < cnt) {
                    float g = accg[mr][reg];
                    float u = accu[mr][reg];
                    float hv = (g / (1.f + __expf(-g))) * u;
                    hbuf[(size_t)(off + r) * IDIM + col] = f2bf(hv);
                }
            }
        }
        __syncthreads();
    }
}

// ---------------- kernel 6: down ----------------
// grid (e, mt4-stride, ntile 16); BN=128; 8 waves = 2wr x 4wc; wave 64m x 32n.
__global__ __launch_bounds__(512, 4) void down_mfma(
    const unsigned short* __restrict__ hbuf, const float* __restrict__ down_w,
    const int* __restrict__ offsets, unsigned short* __restrict__ partial) {
    int e = blockIdx.x;
    int ntile = blockIdx.z;
    int off = offsets[e];
    int cnt = offsets[e + 1] - off;
    if (cnt <= 0) return;

    __shared__ unsigned short As[2][BM * BKS];      // 16 KB x2
    __shared__ unsigned short Bd[2][BM * BKS];      // [128n][64k] swz, 16 KB x2

    int tid = threadIdx.x;
    int lane = tid & 63;
    int wave = tid >> 6;
    int wr = wave >> 2, wc = wave & 3;
    int l15 = lane & 15, lg4 = lane >> 4;

    // B staging: 512 thr = 64 n-pair x 8 k-chunk
    int nI2 = tid & 63, kC = tid >> 6;
    int brow0 = nI2 * 2;
    int bslot = (kC ^ (nI2 & 7)) * 8;
    const float* bsrc = down_w + (size_t)e * IDIM * HDIM
                        + (size_t)(kC * 8) * HDIM + ntile * 128 + nI2 * 2;

    for (int mt = blockIdx.y; mt * BM < cnt; mt += gridDim.y) {
        int m0 = mt * BM;
        const unsigned short* aq[2];
        #pragma unroll
        for (int q = 0; q < 2; ++q) {
            int row = q * 64 + (tid >> 3);
            int rr = m0 + row;
            if (rr >= cnt) rr = cnt - 1;
            aq[q] = hbuf + (size_t)(off + rr) * IDIM + (((tid & 7) ^ (row & 7)) * 8);
        }
        f32x4 acc[4][2] = {};

        // prologue
        #pragma unroll
        for (int q = 0; q < 2; ++q)
            gload_lds16(aq[q], &As[0][(q * 512 + tid) * 8]);
        float2 Bv[8];
        #pragma unroll
        for (int i = 0; i < 8; ++i)
            Bv[i] = *(const float2*)(bsrc + (size_t)i * HDIM);

        for (int ks = 0; ks < IDIM / BKS; ++ks) {
            int p = ks & 1;
            {
                uint4 w0, w1;
                w0.x = cvtpk(Bv[0].x, Bv[1].x); w0.y = cvtpk(Bv[2].x, Bv[3].x);
                w0.z = cvtpk(Bv[4].x, Bv[5].x); w0.w = cvtpk(Bv[6].x, Bv[7].x);
                w1.x = cvtpk(Bv[0].y, Bv[1].y); w1.y = cvtpk(Bv[2].y, Bv[3].y);
                w1.z = cvtpk(Bv[4].y, Bv[5].y); w1.w = cvtpk(Bv[6].y, Bv[7].y);
                *(uint4*)&Bd[p][brow0 * BKS + bslot] = w0;
                *(uint4*)&Bd[p][(brow0 + 1) * BKS + bslot] = w1;
            }
            __syncthreads();
            if (ks + 1 < IDIM / BKS) {
                int k1 = (ks + 1) * BKS;
                #pragma unroll
                for (int q = 0; q < 2; ++q)
                    gload_lds16(aq[q] + k1, &As[p ^ 1][(q * 512 + tid) * 8]);
                #pragma unroll
                for (int i = 0; i < 8; ++i)
                    Bv[i] = *(const float2*)(bsrc + (size_t)(k1 + i) * HDIM);
            }
            #pragma unroll
            for (int kk = 0; kk < 2; ++kk) {
                int jk = kk * 4 + lg4;
                s16x8 a[4], b[2];
                #pragma unroll
                for (int mr = 0; mr < 4; ++mr) {
                    int r = wr * 64 + mr * 16 + l15;
                    a[mr] = *(const s16x8*)&As[p][r * BKS + ((jk ^ (r & 7)) * 8)];
                }
                #pragma unroll
                for (int nr = 0; nr < 2; ++nr) {
                    int row = wc * 32 + nr * 16 + l15;
                    b[nr] = *(const s16x8*)&Bd[p][row * BKS + ((jk ^ ((row >> 1) & 7)) * 8)];
                }
                #pragma unroll
                for (int mr = 0; mr < 4; ++mr)
                    #pragma unroll
                    for (int nr = 0; nr < 2; ++nr)
                        acc[mr][nr] = __builtin_amdgcn_mfma_f32_16x16x32_bf16(
                            a[mr], b[nr], acc[mr][nr], 0, 0, 0);
            }
        }

        #pragma unroll
        for (int mr = 0; mr < 4; ++mr)
            #pragma unroll
            for (int nr = 0; nr < 2; ++nr) {
                int col = ntile * 128 + wc * 32 + nr * 16 + l15;
                #pragma unroll
                for (int reg = 0; reg < 4; ++reg) {
                    int r = m0 + wr * 64 + mr * 16 + lg4 * 4 + reg;
                    if (r < cnt)
                        partial[(size_t)(off + r) * HDIM + col] = f2bf(acc[mr][nr][reg]);
                }
            }
        __syncthreads();
    }
}

// ---------------- kernel 7: weighted reduce ----------------
__global__ __launch_bounds__(256) void reduce_kernel(
    const unsigned short* __restrict__ partial, const int* __restrict__ slot_of,
    const float* __restrict__ topk_w, float* __restrict__ out) {
    int t = blockIdx.x;
    int j8 = threadIdx.x * 8;
    __shared__ int ss[8];
    __shared__ float sw[8];
    if (threadIdx.x < 8) {
        ss[threadIdx.x] = slot_of[t * TOPK + threadIdx.x];
        sw[threadIdx.x] = topk_w[t * TOPK + threadIdx.x];
    }
    __syncthreads();
    float acc[8] = {};
    #pragma unroll
    for (int k = 0; k < TOPK; ++k) {
        u16x8 v = *(const u16x8*)&partial[(size_t)ss[k] * HDIM + j8];
        float w = sw[k];
        #pragma unroll
        for (int i = 0; i < 8; ++i)
            acc[i] = fmaf(w, bf_to_f((unsigned short)v[i]), acc[i]);
    }
    float4 o0 = {acc[0], acc[1], acc[2], acc[3]};
    float4 o1 = {acc[4], acc[5], acc[6], acc[7]};
    *(float4*)&out[(size_t)t * HDIM + j8] = o0;
    *(float4*)&out[(size_t)t * HDIM + j8 + 4] = o1;
}

extern "C" void kernel_launch(void* const* d_in, const int* in_sizes, int n_in,
                              void* d_out, int out_size, void* d_ws, size_t ws_size,
                              hipStream_t stream) {
    const float* x  = (const float*)d_in[0];
    const float* rw = (const float*)d_in[1];
    const float* gw = (const float*)d_in[2];
    const float* uw = (const float*)d_in[3];
    const float* dw = (const float*)d_in[4];
    float* out = (float*)d_out;
    float* logits = out + OUT_OFF;

    char* ws = (char*)d_ws;
    int*   topk_idx   = (int*)(ws + WS_TOPK_IDX);
    float* topk_w     = (float*)(ws + WS_TOPK_W);
    int*   pair_token = (int*)(ws + WS_PAIR_TOK);
    int*   slot_of    = (int*)(ws + WS_SLOT_OF);
    int*   counts     = (int*)(ws + WS_COUNTS);
    int*   offsets    = (int*)(ws + WS_OFFSETS);
    int*   cursor     = (int*)(ws + WS_CURSOR);
    unsigned short* hbuf    = (unsigned short*)(ws + WS_H);
    unsigned short* partial = (unsigned short*)(ws + WS_PARTIAL);
    unsigned short* xb      = (unsigned short*)(ws + WS_XB);

    hipMemsetAsync(counts, 0, NEXP * sizeof(int), stream);
    xbf_kernel<<<T_TOK * HDIM / (256 * 8), 256, 0, stream>>>(x, xb);
    router_kernel<<<T_TOK / 4, 256, 0, stream>>>(x, rw, logits);
    topk_kernel<<<T_TOK, 64, 0, stream>>>(logits, topk_idx, topk_w, counts);
    scan_kernel<<<1, 64, 0, stream>>>(counts, offsets, cursor);
    scatter_kernel<<<NPAIR / 256, 256, 0, stream>>>(topk_idx, offsets, cursor, pair_token, slot_of);
    gateup_mfma<<<dim3(NEXP, 4, IDIM / 64), 512, 0, stream>>>(xb, gw, uw, offsets, pair_token, hbuf);
    down_mfma<<<dim3(NEXP, 4, HDIM / 128), 512, 0, stream>>>(hbuf, dw, offsets, partial);
    reduce_kernel<<<dim3(T_TOK, 1), 256, 0, stream>>>(partial, slot_of, topk_w, out);
}